// Round 1
// baseline (10442.640 us; speedup 1.0000x reference)
//
#include <hip/hip_runtime.h>
#include <hip/hip_fp16.h>
#include <cstdint>
#include <cstddef>

// Problem constants (T, B, V, HID, L) from the reference.
#define TT 1024
#define BB 64
#define VV 256
#define HH 512
static const size_t TBH = (size_t)TT * BB * HH;   // 33,554,432 floats

typedef _Float16 half2v __attribute__((ext_vector_type(2)));
union U32H2 { unsigned int u; half2v h; };

__device__ __forceinline__ unsigned pack_f16x2(float a, float b) {
    __half ha = __float2half_rn(a);
    __half hb = __float2half_rn(b);
    return (unsigned)__half_as_ushort(ha) | ((unsigned)__half_as_ushort(hb) << 16);
}

// ---------------------------------------------------------------------------
// Weight prep: f16-pair packed recurrent weights (Wq[i][jp] = {Wh[i][2jp],
// Wh[i][2jp+1]}) and transposed fp32 input-projection weights Wt[k][n].
// ---------------------------------------------------------------------------
__global__ void pack_weights(const float* __restrict__ Wnet,
                             const float* __restrict__ Wdeep,
                             unsigned* __restrict__ Wq0, unsigned* __restrict__ Wq1,
                             float* __restrict__ Wt0, float* __restrict__ Wt1) {
    int id = blockIdx.x * 256 + threadIdx.x;
    const int NQ = HH * (HH / 2);       // 512*256 = 131072
    const int NT0 = VV * HH;            // 131072
    const int NT1 = HH * HH;            // 262144
    if (id < NQ) {
        int i = id >> 8, jp = id & 255;
        const float* row = Wnet + (size_t)i * (VV + HH) + VV;   // Wh0[i][:]
        Wq0[id] = pack_f16x2(row[2 * jp], row[2 * jp + 1]);
        return;
    }
    id -= NQ;
    if (id < NQ) {
        int i = id >> 8, jp = id & 255;
        const float* row = Wdeep + (size_t)i * (2 * HH) + HH;   // Wh1[i][:]
        Wq1[id] = pack_f16x2(row[2 * jp], row[2 * jp + 1]);
        return;
    }
    id -= NQ;
    if (id < NT0) {
        int k = id >> 9, n = id & 511;
        Wt0[id] = Wnet[(size_t)n * (VV + HH) + k];              // Wx0^T
        return;
    }
    id -= NT0;
    if (id < NT1) {
        int k = id >> 9, n = id & 511;
        Wt1[id] = Wdeep[(size_t)n * (2 * HH) + k];              // Wx1^T
        return;
    }
}

// ---------------------------------------------------------------------------
// Input-projection GEMM: C[M,512] = A[M,K] @ Wt[K,512] + bias.  In-place safe
// for A == C: the 32-row A tile is fully staged to LDS before any C write,
// and each block only reads/writes its own 32 rows.
// Block: 1024 threads. thread t: row-group rg = t>>6 (2 rows), cols (t&63)*8.
// ---------------------------------------------------------------------------
__launch_bounds__(1024)
__global__ void xproj_gemm(const float* __restrict__ A,
                           const float* __restrict__ Wt,
                           const float* __restrict__ bias,
                           float* __restrict__ C, int K) {
    extern __shared__ float As[];          // 32 * K floats
    const int m0 = blockIdx.x * 32;
    const int t = threadIdx.x;

    // stage A tile (coalesced float4)
    const int nf4 = 8 * K;                 // 32*K/4
    const float4* Ag = (const float4*)(A + (size_t)m0 * K);
    float4* As4 = (float4*)As;
    for (int idx = t; idx < nf4; idx += 1024) As4[idx] = Ag[idx];
    __syncthreads();

    const int rg = t >> 6;                 // wave id, uniform per wave
    const int n0 = (t & 63) * 8;

    float acc[2][8];
#pragma unroll
    for (int r = 0; r < 2; ++r)
#pragma unroll
        for (int c = 0; c < 8; ++c) acc[r][c] = 0.f;

    const float* a0p = As + (size_t)(rg * 2 + 0) * K;
    const float* a1p = As + (size_t)(rg * 2 + 1) * K;

#pragma unroll 2
    for (int k = 0; k < K; ++k) {
        const float a0 = a0p[k];
        const float a1 = a1p[k];
        const float4 w0 = *(const float4*)(Wt + (size_t)k * 512 + n0);
        const float4 w1 = *(const float4*)(Wt + (size_t)k * 512 + n0 + 4);
        acc[0][0] += a0 * w0.x; acc[0][1] += a0 * w0.y;
        acc[0][2] += a0 * w0.z; acc[0][3] += a0 * w0.w;
        acc[0][4] += a0 * w1.x; acc[0][5] += a0 * w1.y;
        acc[0][6] += a0 * w1.z; acc[0][7] += a0 * w1.w;
        acc[1][0] += a1 * w0.x; acc[1][1] += a1 * w0.y;
        acc[1][2] += a1 * w0.z; acc[1][3] += a1 * w0.w;
        acc[1][4] += a1 * w1.x; acc[1][5] += a1 * w1.y;
        acc[1][6] += a1 * w1.z; acc[1][7] += a1 * w1.w;
    }

    float bv[8];
#pragma unroll
    for (int c = 0; c < 8; ++c) bv[c] = bias[n0 + c];

    float* Crow0 = C + (size_t)(m0 + rg * 2) * 512 + n0;
    float* Crow1 = Crow0 + 512;
    float4 o;
    o = make_float4(acc[0][0] + bv[0], acc[0][1] + bv[1], acc[0][2] + bv[2], acc[0][3] + bv[3]);
    *(float4*)(Crow0) = o;
    o = make_float4(acc[0][4] + bv[4], acc[0][5] + bv[5], acc[0][6] + bv[6], acc[0][7] + bv[7]);
    *(float4*)(Crow0 + 4) = o;
    o = make_float4(acc[1][0] + bv[0], acc[1][1] + bv[1], acc[1][2] + bv[2], acc[1][3] + bv[3]);
    *(float4*)(Crow1) = o;
    o = make_float4(acc[1][4] + bv[4], acc[1][5] + bv[5], acc[1][6] + bv[6], acc[1][7] + bv[7]);
    *(float4*)(Crow1 + 4) = o;
}

// ---------------------------------------------------------------------------
// Sequential RNN scan, one workgroup per batch element, in-place over the
// pre-activation buffer.  h replicated per-wave in VGPRs as f16 pairs;
// broadcast via v_readlane; MACs via v_dot2_f32_f16 (fp32 accumulate).
// ---------------------------------------------------------------------------
__launch_bounds__(512)
__global__ void rnn_scan(const unsigned* __restrict__ Wq,
                         const float* __restrict__ h0,
                         float* __restrict__ states,
                         float* __restrict__ last) {
    __shared__ float hsh[HH];
    const int b = blockIdx.x;
    const int i = threadIdx.x;
    const int lane = i & 63;

    float hn = h0[(size_t)b * HH + i];
    hsh[i] = hn;
    __syncthreads();

    unsigned hp[4];
    {
        const float2* hp2 = (const float2*)hsh;
#pragma unroll
        for (int r = 0; r < 4; ++r) {
            float2 v = hp2[r * 64 + lane];
            hp[r] = pack_f16x2(v.x, v.y);
        }
    }

    const uint4* Wrow = (const uint4*)(Wq + (size_t)i * 256);

    for (int tstep = 0; tstep < TT; ++tstep) {
        float* pre = states + ((size_t)tstep * BB + b) * HH;
        float acc = pre[i];

#pragma unroll
        for (int q = 0; q < 64; ++q) {
            uint4 w = Wrow[q];
#pragma unroll
            for (int u = 0; u < 4; ++u) {
                const int jp = q * 4 + u;
                unsigned sv = (unsigned)__builtin_amdgcn_readlane((int)hp[jp >> 6], jp & 63);
                unsigned wv = (u == 0) ? w.x : (u == 1) ? w.y : (u == 2) ? w.z : w.w;
                U32H2 uw; uw.u = wv;
                U32H2 us; us.u = sv;
#if __has_builtin(__builtin_amdgcn_fdot2)
                acc = __builtin_amdgcn_fdot2(uw.h, us.h, acc, false);
#else
                acc += (float)uw.h[0] * (float)us.h[0] + (float)uw.h[1] * (float)us.h[1];
#endif
            }
        }

        hn = tanhf(acc);
        pre[i] = hn;                         // overwrite pre with state (in-place)

        __syncthreads();                     // prior hp reads done everywhere
        hsh[i] = hn;
        __syncthreads();
        const float2* hp2 = (const float2*)hsh;
#pragma unroll
        for (int r = 0; r < 4; ++r) {
            float2 v = hp2[r * 64 + lane];
            hp[r] = pack_f16x2(v.x, v.y);
        }
    }

    last[(size_t)b * HH + i] = hn;
}

// ---------------------------------------------------------------------------
extern "C" void kernel_launch(void* const* d_in, const int* in_sizes, int n_in,
                              void* d_out, int out_size, void* d_ws, size_t ws_size,
                              hipStream_t stream) {
    (void)in_sizes; (void)n_in; (void)out_size; (void)ws_size;
    const float* inputs = (const float*)d_in[0];   // (T,B,V)
    const float* H      = (const float*)d_in[1];   // (L,B,HID)
    const float* Wnet   = (const float*)d_in[2];   // (HID, V+HID)
    const float* bnet   = (const float*)d_in[3];   // (HID,)
    const float* Wdeep  = (const float*)d_in[4];   // (HID, 2*HID)
    const float* bdeep  = (const float*)d_in[5];   // (HID,)
    float* out = (float*)d_out;

    // workspace layout (2.5 MB total)
    unsigned* Wq0 = (unsigned*)d_ws;               // 131072 u32
    unsigned* Wq1 = Wq0 + HH * (HH / 2);           // 131072 u32
    float* Wt0 = (float*)(Wq1 + HH * (HH / 2));    // 131072 f32
    float* Wt1 = Wt0 + VV * HH;                    // 262144 f32

    // 1) pack weights
    hipLaunchKernelGGL(pack_weights, dim3(2560), dim3(256), 0, stream,
                       Wnet, Wdeep, Wq0, Wq1, Wt0, Wt1);

    // 2) pre0 = inputs @ Wx0^T + b_net  -> d_out[0:TBH]
    hipLaunchKernelGGL(xproj_gemm, dim3((TT * BB) / 32), dim3(1024),
                       32 * VV * sizeof(float), stream,
                       inputs, Wt0, bnet, out, VV);

    // 3) layer-0 scan (in-place pre0 -> states0), last -> tail slot 0
    hipLaunchKernelGGL(rnn_scan, dim3(BB), dim3(HH), 0, stream,
                       Wq0, H, out, out + TBH);

    // 4) pre1 = states0 @ Wx1^T + b_deep (in-place over d_out)
    hipLaunchKernelGGL(xproj_gemm, dim3((TT * BB) / 32), dim3(1024),
                       32 * HH * sizeof(float), stream,
                       out, Wt1, bdeep, out, HH);

    // 5) layer-1 scan (in-place pre1 -> states1), last -> tail slot 1
    hipLaunchKernelGGL(rnn_scan, dim3(BB), dim3(HH), 0, stream,
                       Wq1, H + (size_t)BB * HH, out, out + TBH + (size_t)BB * HH);
}

// Round 2
// 9989.466 us; speedup vs baseline: 1.0454x; 1.0454x over previous
//
#include <hip/hip_runtime.h>
#include <hip/hip_fp16.h>
#include <cstdint>
#include <cstddef>

// Problem constants (T, B, V, HID, L) from the reference.
#define TT 1024
#define BB 64
#define VV 256
#define HH 512
static const size_t TBH = (size_t)TT * BB * HH;   // 33,554,432 floats

#define AGENT __HIP_MEMORY_SCOPE_AGENT

typedef _Float16 half2v __attribute__((ext_vector_type(2)));
union U32H2 { unsigned int u; half2v h; };

__device__ __forceinline__ unsigned pack_f16x2(float a, float b) {
    __half ha = __float2half_rn(a);
    __half hb = __float2half_rn(b);
    return (unsigned)__half_as_ushort(ha) | ((unsigned)__half_as_ushort(hb) << 16);
}

__device__ __forceinline__ float tanh_fast(float x) {
    // tanh(x) = sign(x) * (1 - e^-2|x|) / (1 + e^-2|x|)
    float ax = fabsf(x);
    float e = __expf(-2.0f * ax);
    float r = (1.0f - e) / (1.0f + e);
    return copysignf(r, x);
}

// ---------------------------------------------------------------------------
// Weight prep: f16-pair packed recurrent weights (Wq[i][jp] = {Wh[i][2jp],
// Wh[i][2jp+1]}) and transposed fp32 input-projection weights Wt[k][n].
// ---------------------------------------------------------------------------
__global__ void pack_weights(const float* __restrict__ Wnet,
                             const float* __restrict__ Wdeep,
                             unsigned* __restrict__ Wq0, unsigned* __restrict__ Wq1,
                             float* __restrict__ Wt0, float* __restrict__ Wt1) {
    int id = blockIdx.x * 256 + threadIdx.x;
    const int NQ = HH * (HH / 2);       // 131072
    const int NT0 = VV * HH;            // 131072
    const int NT1 = HH * HH;            // 262144
    if (id < NQ) {
        int i = id >> 8, jp = id & 255;
        const float* row = Wnet + (size_t)i * (VV + HH) + VV;   // Wh0[i][:]
        Wq0[id] = pack_f16x2(row[2 * jp], row[2 * jp + 1]);
        return;
    }
    id -= NQ;
    if (id < NQ) {
        int i = id >> 8, jp = id & 255;
        const float* row = Wdeep + (size_t)i * (2 * HH) + HH;   // Wh1[i][:]
        Wq1[id] = pack_f16x2(row[2 * jp], row[2 * jp + 1]);
        return;
    }
    id -= NQ;
    if (id < NT0) {
        int k = id >> 9, n = id & 511;
        Wt0[id] = Wnet[(size_t)n * (VV + HH) + k];              // Wx0^T
        return;
    }
    id -= NT0;
    if (id < NT1) {
        int k = id >> 9, n = id & 511;
        Wt1[id] = Wdeep[(size_t)n * (2 * HH) + k];              // Wx1^T
        return;
    }
}

// ---------------------------------------------------------------------------
// Input-projection GEMM: C[M,512] = A[M,K] @ Wt[K,512] + bias.  In-place safe
// for A == C (32-row A tile fully staged to LDS before any C write).
// ---------------------------------------------------------------------------
__launch_bounds__(1024)
__global__ void xproj_gemm(const float* __restrict__ A,
                           const float* __restrict__ Wt,
                           const float* __restrict__ bias,
                           float* __restrict__ C, int K) {
    extern __shared__ float As[];          // 32 * K floats
    const int m0 = blockIdx.x * 32;
    const int t = threadIdx.x;

    const int nf4 = 8 * K;
    const float4* Ag = (const float4*)(A + (size_t)m0 * K);
    float4* As4 = (float4*)As;
    for (int idx = t; idx < nf4; idx += 1024) As4[idx] = Ag[idx];
    __syncthreads();

    const int rg = t >> 6;
    const int n0 = (t & 63) * 8;

    float acc[2][8];
#pragma unroll
    for (int r = 0; r < 2; ++r)
#pragma unroll
        for (int c = 0; c < 8; ++c) acc[r][c] = 0.f;

    const float* a0p = As + (size_t)(rg * 2 + 0) * K;
    const float* a1p = As + (size_t)(rg * 2 + 1) * K;

#pragma unroll 2
    for (int k = 0; k < K; ++k) {
        const float a0 = a0p[k];
        const float a1 = a1p[k];
        const float4 w0 = *(const float4*)(Wt + (size_t)k * 512 + n0);
        const float4 w1 = *(const float4*)(Wt + (size_t)k * 512 + n0 + 4);
        acc[0][0] += a0 * w0.x; acc[0][1] += a0 * w0.y;
        acc[0][2] += a0 * w0.z; acc[0][3] += a0 * w0.w;
        acc[0][4] += a0 * w1.x; acc[0][5] += a0 * w1.y;
        acc[0][6] += a0 * w1.z; acc[0][7] += a0 * w1.w;
        acc[1][0] += a1 * w0.x; acc[1][1] += a1 * w0.y;
        acc[1][2] += a1 * w0.z; acc[1][3] += a1 * w0.w;
        acc[1][4] += a1 * w1.x; acc[1][5] += a1 * w1.y;
        acc[1][6] += a1 * w1.z; acc[1][7] += a1 * w1.w;
    }

    float bv[8];
#pragma unroll
    for (int c = 0; c < 8; ++c) bv[c] = bias[n0 + c];

    float* Crow0 = C + (size_t)(m0 + rg * 2) * 512 + n0;
    float* Crow1 = Crow0 + 512;
    float4 o;
    o = make_float4(acc[0][0] + bv[0], acc[0][1] + bv[1], acc[0][2] + bv[2], acc[0][3] + bv[3]);
    *(float4*)(Crow0) = o;
    o = make_float4(acc[0][4] + bv[4], acc[0][5] + bv[5], acc[0][6] + bv[6], acc[0][7] + bv[7]);
    *(float4*)(Crow0 + 4) = o;
    o = make_float4(acc[1][0] + bv[0], acc[1][1] + bv[1], acc[1][2] + bv[2], acc[1][3] + bv[3]);
    *(float4*)(Crow1) = o;
    o = make_float4(acc[1][4] + bv[4], acc[1][5] + bv[5], acc[1][6] + bv[6], acc[1][7] + bv[7]);
    *(float4*)(Crow1 + 4) = o;
}

// ---------------------------------------------------------------------------
// RNN scan with REGISTER-RESIDENT weights, 2 CUs per batch element (K-split).
// WG w: batch b = w>>1, K-half s = w&1 (k in [s*256, s*256+256)).
// Thread i holds rows {i, i+256} over its K-half: 2 x 32 uint4 of f16x2
// weights in VGPRs (loaded once).  Each step: 384 VALU ops of dot2+readlane,
// then the pair exchanges PARTIAL SUMS via agent-scope atomics.  CU s
// finalizes rows [s*256, s*256+256) == exactly the h-half it needs next step,
// so h itself never crosses CUs.
// ---------------------------------------------------------------------------
__launch_bounds__(256, 1)
__global__ void rnn_scan2(const unsigned* __restrict__ Wq,   // [512][256] f16x2
                          const float* __restrict__ h0,      // [B][512]
                          float* __restrict__ states,        // [T][B][512] in:pre out:h
                          float* __restrict__ last,          // [B][512]
                          unsigned* __restrict__ X,          // [B][2][2][256]
                          unsigned* __restrict__ flags) {    // [B][2]
    __shared__ float hsh[2][256];

    const int w = blockIdx.x;
    const int b = w >> 1;
    const int s = w & 1;
    const int i = threadIdx.x;          // 0..255
    const int lane = i & 63;

    // rows owned (partials): row_lo = i, row_hi = i+256.  Finalized row:
    const int rfin = s * 256 + i;
    // K-half pair range: jp_global in [s*128, s*128+128)

    // --- load weights into registers (once) ---
    uint4 wlo[32], whi[32];
    {
        const uint4* Wl = (const uint4*)(Wq + (size_t)i * 256 + s * 128);
        const uint4* Wh_ = (const uint4*)(Wq + (size_t)(i + 256) * 256 + s * 128);
#pragma unroll
        for (int q = 0; q < 32; ++q) wlo[q] = Wl[q];
#pragma unroll
        for (int q = 0; q < 32; ++q) whi[q] = Wh_[q];
    }

    // --- init hp (h of my K-half, f16x2, replicated per wave) ---
    unsigned hp[2];
    {
        const float2* h2 = (const float2*)(h0 + (size_t)b * HH);
#pragma unroll
        for (int rr = 0; rr < 2; ++rr) {
            float2 v = h2[s * 128 + rr * 64 + lane];
            hp[rr] = pack_f16x2(v.x, v.y);
        }
    }

    unsigned* Xmine = X + ((size_t)(b * 2 + s)) * 2 * 256;
    unsigned* Xpart = X + ((size_t)(b * 2 + (s ^ 1))) * 2 * 256;
    unsigned* fmine = flags + b * 2 + s;
    unsigned* fpart = flags + b * 2 + (s ^ 1);

    float h = 0.f;
    for (int t = 0; t < TT; ++t) {
        const size_t rowbase = ((size_t)t * BB + b) * HH;
        float pre_mine = states[rowbase + rfin];     // prefetched; used late

        float accL[4] = {0.f, 0.f, 0.f, 0.f};
        float accH[4] = {0.f, 0.f, 0.f, 0.f};
#pragma unroll
        for (int q = 0; q < 32; ++q) {
            const uint4 wl = wlo[q];
            const uint4 wh_ = whi[q];
#pragma unroll
            for (int u = 0; u < 4; ++u) {
                unsigned sv = (unsigned)__builtin_amdgcn_readlane((int)hp[q >> 4], (q * 4 + u) & 63);
                U32H2 us; us.u = sv;
                unsigned wluv = (u == 0) ? wl.x : (u == 1) ? wl.y : (u == 2) ? wl.z : wl.w;
                unsigned whuv = (u == 0) ? wh_.x : (u == 1) ? wh_.y : (u == 2) ? wh_.z : wh_.w;
                U32H2 ua; ua.u = wluv;
                U32H2 uc; uc.u = whuv;
#if __has_builtin(__builtin_amdgcn_fdot2)
                accL[u] = __builtin_amdgcn_fdot2(ua.h, us.h, accL[u], false);
                accH[u] = __builtin_amdgcn_fdot2(uc.h, us.h, accH[u], false);
#else
                accL[u] += (float)ua.h[0] * (float)us.h[0] + (float)ua.h[1] * (float)us.h[1];
                accH[u] += (float)uc.h[0] * (float)us.h[0] + (float)uc.h[1] * (float)us.h[1];
#endif
            }
        }
        float pLo = (accL[0] + accL[1]) + (accL[2] + accL[3]);
        float pHi = (accH[0] + accH[1]) + (accH[2] + accH[3]);
        float part_mine = (s == 0) ? pLo : pHi;      // partial for rfin
        float part_pub  = (s == 0) ? pHi : pLo;      // partial for partner's row

        const int p = t & 1;
        __hip_atomic_store(&Xmine[p * 256 + i], __float_as_uint(part_pub),
                           __ATOMIC_RELAXED, AGENT);
        __syncthreads();                              // all stores drained (vmcnt 0)
        if (i == 0) {
            __hip_atomic_store(fmine, (unsigned)(t + 1), __ATOMIC_RELEASE, AGENT);
            while (__hip_atomic_load(fpart, __ATOMIC_ACQUIRE, AGENT) < (unsigned)(t + 1)) {
                __builtin_amdgcn_s_sleep(1);
            }
        }
        __syncthreads();

        float part_other = __uint_as_float(
            __hip_atomic_load(&Xpart[p * 256 + i], __ATOMIC_RELAXED, AGENT));

        h = tanh_fast(pre_mine + part_mine + part_other);
        states[rowbase + rfin] = h;

        hsh[p][i] = h;
        __syncthreads();
        const float2* hh = (const float2*)hsh[p];
#pragma unroll
        for (int rr = 0; rr < 2; ++rr) {
            float2 v = hh[rr * 64 + lane];
            hp[rr] = pack_f16x2(v.x, v.y);
        }
    }

    last[(size_t)b * HH + rfin] = h;
}

// ---------------------------------------------------------------------------
extern "C" void kernel_launch(void* const* d_in, const int* in_sizes, int n_in,
                              void* d_out, int out_size, void* d_ws, size_t ws_size,
                              hipStream_t stream) {
    (void)in_sizes; (void)n_in; (void)out_size; (void)ws_size;
    const float* inputs = (const float*)d_in[0];   // (T,B,V)
    const float* H      = (const float*)d_in[1];   // (L,B,HID)
    const float* Wnet   = (const float*)d_in[2];   // (HID, V+HID)
    const float* bnet   = (const float*)d_in[3];   // (HID,)
    const float* Wdeep  = (const float*)d_in[4];   // (HID, 2*HID)
    const float* bdeep  = (const float*)d_in[5];   // (HID,)
    float* out = (float*)d_out;

    // workspace layout
    unsigned* flags0 = (unsigned*)d_ws;            // 128 u32
    unsigned* flags1 = flags0 + 128;               // 128 u32
    unsigned* X      = flags1 + 128;               // 65536 u32 (256 KB)
    unsigned* Wq0    = X + 65536;                  // 131072 u32
    unsigned* Wq1    = Wq0 + HH * (HH / 2);        // 131072 u32
    float* Wt0 = (float*)(Wq1 + HH * (HH / 2));    // 131072 f32
    float* Wt1 = Wt0 + VV * HH;                    // 262144 f32

    // flags must start at 0 (ws is poisoned 0xAA before every launch)
    hipMemsetAsync(d_ws, 0, 2 * 128 * sizeof(unsigned), stream);

    // 1) pack weights
    hipLaunchKernelGGL(pack_weights, dim3(2560), dim3(256), 0, stream,
                       Wnet, Wdeep, Wq0, Wq1, Wt0, Wt1);

    // 2) pre0 = inputs @ Wx0^T + b_net  -> d_out[0:TBH]
    hipLaunchKernelGGL(xproj_gemm, dim3((TT * BB) / 32), dim3(1024),
                       32 * VV * sizeof(float), stream,
                       inputs, Wt0, bnet, out, VV);

    // 3) layer-0 scan
    hipLaunchKernelGGL(rnn_scan2, dim3(2 * BB), dim3(256), 0, stream,
                       Wq0, H, out, out + TBH, X, flags0);

    // 4) pre1 = states0 @ Wx1^T + b_deep (in-place over d_out)
    hipLaunchKernelGGL(xproj_gemm, dim3((TT * BB) / 32), dim3(1024),
                       32 * HH * sizeof(float), stream,
                       out, Wt1, bdeep, out, HH);

    // 5) layer-1 scan
    hipLaunchKernelGGL(rnn_scan2, dim3(2 * BB), dim3(256), 0, stream,
                       Wq1, H + (size_t)BB * HH, out, out + TBH + (size_t)BB * HH,
                       X, flags1);
}

// Round 3
// 4053.869 us; speedup vs baseline: 2.5760x; 2.4642x over previous
//
#include <hip/hip_runtime.h>
#include <hip/hip_fp16.h>
#include <cstdint>
#include <cstddef>

// Problem constants (T, B, V, HID, L) from the reference.
#define TT 1024
#define BB 64
#define VV 256
#define HH 512
static const size_t TBH = (size_t)TT * BB * HH;   // 33,554,432 floats

#define AGENT __HIP_MEMORY_SCOPE_AGENT

typedef _Float16 half2v __attribute__((ext_vector_type(2)));
union U32H2 { unsigned u; half2v h; };

__device__ __forceinline__ unsigned pack_f16x2(float a, float b) {
    __half ha = __float2half_rn(a);
    __half hb = __float2half_rn(b);
    return (unsigned)__half_as_ushort(ha) | ((unsigned)__half_as_ushort(hb) << 16);
}

__device__ __forceinline__ float tanh_fast(float x) {
    // tanh(x) = sign(x) * (1 - e^-2|x|) / (1 + e^-2|x|)
    float ax = fabsf(x);
    float e = __expf(-2.0f * ax);
    float r = (1.0f - e) * __builtin_amdgcn_rcpf(1.0f + e);
    return copysignf(r, x);
}

__device__ __forceinline__ float fdot2(unsigned w, unsigned h, float acc) {
    U32H2 uw; uw.u = w;
    U32H2 uh; uh.u = h;
#if __has_builtin(__builtin_amdgcn_fdot2)
    return __builtin_amdgcn_fdot2(uw.h, uh.h, acc, false);
#else
    return acc + (float)uw.h[0] * (float)uh.h[0] + (float)uw.h[1] * (float)uh.h[1];
#endif
}

// ---------------------------------------------------------------------------
// Weight prep:
//  Wq0/Wq1 : recurrent Wh rows as f16x2 k-pairs   [512 rows][256 pairs]
//  Wp0/Wp1 : input-proj Wx^T as f16x2 k-pairs     [K/2 pairs][512 cols]
// ---------------------------------------------------------------------------
__global__ void pack_weights(const float* __restrict__ Wnet,
                             const float* __restrict__ Wdeep,
                             unsigned* __restrict__ Wq0, unsigned* __restrict__ Wq1,
                             unsigned* __restrict__ Wp0, unsigned* __restrict__ Wp1) {
    int id = blockIdx.x * 256 + threadIdx.x;
    const int NQ  = HH * (HH / 2);     // 131072
    const int NP0 = (VV / 2) * HH;     // 65536
    const int NP1 = (HH / 2) * HH;     // 131072
    if (id < NQ) {
        int i = id >> 8, jp = id & 255;
        const float* row = Wnet + (size_t)i * (VV + HH) + VV;   // Wh0[i][:]
        Wq0[id] = pack_f16x2(row[2 * jp], row[2 * jp + 1]);
        return;
    }
    id -= NQ;
    if (id < NQ) {
        int i = id >> 8, jp = id & 255;
        const float* row = Wdeep + (size_t)i * (2 * HH) + HH;   // Wh1[i][:]
        Wq1[id] = pack_f16x2(row[2 * jp], row[2 * jp + 1]);
        return;
    }
    id -= NQ;
    if (id < NP0) {
        int k2 = id >> 9, n = id & 511;                          // Wx0[n][2k2..]
        const float* row = Wnet + (size_t)n * (VV + HH);
        Wp0[id] = pack_f16x2(row[2 * k2], row[2 * k2 + 1]);
        return;
    }
    id -= NP0;
    if (id < NP1) {
        int k2 = id >> 9, n = id & 511;                          // Wx1[n][2k2..]
        const float* row = Wdeep + (size_t)n * (2 * HH);
        Wp1[id] = pack_f16x2(row[2 * k2], row[2 * k2 + 1]);
        return;
    }
}

// ---------------------------------------------------------------------------
// Input-projection GEMM (f16 dot2): C[M,512] = A[M,K] @ Wx^T + bias.
// A tile converted to f16x2 pairs in LDS (staged fully before any C write ->
// in-place safe for A == C).  Block: 1024 thr; thread t: 2 rows, 8 cols.
// ---------------------------------------------------------------------------
__device__ __forceinline__ void dot8(float* acc, unsigned a, uint4 w0, uint4 w1) {
    acc[0] = fdot2(w0.x, a, acc[0]);
    acc[1] = fdot2(w0.y, a, acc[1]);
    acc[2] = fdot2(w0.z, a, acc[2]);
    acc[3] = fdot2(w0.w, a, acc[3]);
    acc[4] = fdot2(w1.x, a, acc[4]);
    acc[5] = fdot2(w1.y, a, acc[5]);
    acc[6] = fdot2(w1.z, a, acc[6]);
    acc[7] = fdot2(w1.w, a, acc[7]);
}

__launch_bounds__(1024)
__global__ void xproj_f16(const float* __restrict__ A,
                          const unsigned* __restrict__ Wp,   // [K/2][512] f16x2
                          const float* __restrict__ bias,
                          float* __restrict__ C, int K) {
    extern __shared__ unsigned As2[];      // 32 rows * K/2 pairs
    const int m0 = blockIdx.x * 32;
    const int t = threadIdx.x;
    const int K2 = K >> 1;

    // stage + convert A tile (coalesced float4 reads)
    const int nf4 = 8 * K;                 // 32*K/4
    const float4* Ag = (const float4*)(A + (size_t)m0 * K);
    for (int idx = t; idx < nf4; idx += 1024) {
        float4 v = Ag[idx];
        As2[idx * 2]     = pack_f16x2(v.x, v.y);
        As2[idx * 2 + 1] = pack_f16x2(v.z, v.w);
    }
    __syncthreads();

    const int rg = t >> 6;                 // 2 rows per thread
    const int n0 = (t & 63) * 8;

    float acc0[8] = {0, 0, 0, 0, 0, 0, 0, 0};
    float acc1[8] = {0, 0, 0, 0, 0, 0, 0, 0};

    const unsigned* a0p = As2 + (size_t)(rg * 2) * K2;
    const unsigned* a1p = a0p + K2;

#pragma unroll 4
    for (int k2 = 0; k2 < K2; k2 += 2) {
        unsigned a00 = a0p[k2], a01 = a0p[k2 + 1];
        unsigned a10 = a1p[k2], a11 = a1p[k2 + 1];
        const uint4 w00 = *(const uint4*)(Wp + (size_t)k2 * 512 + n0);
        const uint4 w01 = *(const uint4*)(Wp + (size_t)k2 * 512 + n0 + 4);
        const uint4 w10 = *(const uint4*)(Wp + (size_t)(k2 + 1) * 512 + n0);
        const uint4 w11 = *(const uint4*)(Wp + (size_t)(k2 + 1) * 512 + n0 + 4);
        dot8(acc0, a00, w00, w01);
        dot8(acc1, a10, w00, w01);
        dot8(acc0, a01, w10, w11);
        dot8(acc1, a11, w10, w11);
    }

    float bv[8];
#pragma unroll
    for (int c = 0; c < 8; ++c) bv[c] = bias[n0 + c];

    float* Crow0 = C + (size_t)(m0 + rg * 2) * 512 + n0;
    float* Crow1 = Crow0 + 512;
    *(float4*)(Crow0)     = make_float4(acc0[0] + bv[0], acc0[1] + bv[1], acc0[2] + bv[2], acc0[3] + bv[3]);
    *(float4*)(Crow0 + 4) = make_float4(acc0[4] + bv[4], acc0[5] + bv[5], acc0[6] + bv[6], acc0[7] + bv[7]);
    *(float4*)(Crow1)     = make_float4(acc1[0] + bv[0], acc1[1] + bv[1], acc1[2] + bv[2], acc1[3] + bv[3]);
    *(float4*)(Crow1 + 4) = make_float4(acc1[4] + bv[4], acc1[5] + bv[5], acc1[6] + bv[6], acc1[7] + bv[7]);
}

// ---------------------------------------------------------------------------
// RNN scan, 2 CUs per batch element (K-split), register-resident weights.
// Grid: 128 WGs of 512 thr.  b = w&63, s = w>>6  -> pair (b, b+64) lands on
// the SAME XCD under round-robin blockIdx%8 dispatch (64%8==0), so the
// exchange stays in that XCD's L2.  Thread i owns row r=i over K-half s
// (128 f16x2 pairs = 128 VGPRs, loaded once).  Exchange: 64-bit fused
// {tag,payload} relaxed agent atomics, double-buffered by step parity;
// owner threads poll for exact tag (0xAA poison / stale tags never match).
// One __syncthreads per step (h repack via LDS).
// ---------------------------------------------------------------------------
__launch_bounds__(512, 1)
__global__ void rnn_scan3(const unsigned* __restrict__ Wq,   // [512][256] f16x2
                          const float* __restrict__ h0,      // [B][512]
                          float* __restrict__ states,        // [T][B][512] in:pre out:h
                          float* __restrict__ last,          // [B][512]
                          unsigned long long* __restrict__ X) { // [B][2 owner][2 par][256]
    __shared__ float hsh[2][256];

    const int w = blockIdx.x;
    const int b = w & 63;
    const int s = w >> 6;
    const int r = threadIdx.x;          // my row, 0..511
    const int lane = r & 63;
    const int owner = r >> 8;           // WG (s==owner) finalizes row r
    const bool is_owner = (owner == s); // wave-uniform

    // --- weights for row r over K-half s: 32 uint4 in VGPRs ---
    uint4 wreg[32];
    {
        const uint4* Wr = (const uint4*)(Wq + (size_t)r * 256 + s * 128);
#pragma unroll
        for (int q = 0; q < 32; ++q) wreg[q] = Wr[q];
    }

    // --- hp: my K-half of h as f16x2 pairs, replicated per wave ---
    unsigned hp[2];
    {
        const float2* h2 = (const float2*)(h0 + (size_t)b * HH);
#pragma unroll
        for (int rr = 0; rr < 2; ++rr) {
            float2 v = h2[s * 128 + rr * 64 + lane];
            hp[rr] = pack_f16x2(v.x, v.y);
        }
    }

    // exchange slots (same address computed by writer and reader)
    unsigned long long* slotA = X + ((((size_t)b * 2 + owner) * 2 + 0) << 8) + (r & 255);
    unsigned long long* slotB = slotA + 256;

    size_t base = (size_t)b * HH;       // rowbase for t=0
    const size_t tstride = (size_t)BB * HH;

    float pre_cur = 0.f;
    if (is_owner) pre_cur = states[base + r];

    float h = 0.f;
    for (int t = 0; t < TT; ++t) {
        float pre_nxt = 0.f;
        if (is_owner && t + 1 < TT) pre_nxt = states[base + tstride + r];

        // partial for row r over K-half s: 128 dot2
        float a0 = 0.f, a1 = 0.f, a2 = 0.f, a3 = 0.f;
#pragma unroll
        for (int q = 0; q < 32; ++q) {
            const uint4 wv = wreg[q];
            const int j = q * 4;
            unsigned s0 = (unsigned)__builtin_amdgcn_readlane((int)hp[(j + 0) >> 6], (j + 0) & 63);
            unsigned s1 = (unsigned)__builtin_amdgcn_readlane((int)hp[(j + 1) >> 6], (j + 1) & 63);
            unsigned s2 = (unsigned)__builtin_amdgcn_readlane((int)hp[(j + 2) >> 6], (j + 2) & 63);
            unsigned s3 = (unsigned)__builtin_amdgcn_readlane((int)hp[(j + 3) >> 6], (j + 3) & 63);
            a0 = fdot2(wv.x, s0, a0);
            a1 = fdot2(wv.y, s1, a1);
            a2 = fdot2(wv.z, s2, a2);
            a3 = fdot2(wv.w, s3, a3);
        }
        float part = (a0 + a1) + (a2 + a3);

        const int p = t & 1;
        unsigned long long* slot = p ? slotB : slotA;
        if (!is_owner) {
            unsigned long long msg = ((unsigned long long)(unsigned)(t + 1) << 32)
                                   | (unsigned long long)__float_as_uint(part);
            __hip_atomic_store(slot, msg, __ATOMIC_RELAXED, AGENT);
        } else {
            unsigned long long v;
            do {
                v = __hip_atomic_load(slot, __ATOMIC_RELAXED, AGENT);
            } while ((unsigned)(v >> 32) != (unsigned)(t + 1));
            float pother = __uint_as_float((unsigned)v);
            h = tanh_fast(pre_cur + part + pother);
            states[base + r] = h;
            hsh[p][r & 255] = h;
        }
        __syncthreads();

        const float2* hh = (const float2*)hsh[p];
#pragma unroll
        for (int rr = 0; rr < 2; ++rr) {
            float2 vv = hh[rr * 64 + lane];
            hp[rr] = pack_f16x2(vv.x, vv.y);
        }
        pre_cur = pre_nxt;
        base += tstride;
    }

    if (is_owner) last[(size_t)b * HH + r] = h;
}

// ---------------------------------------------------------------------------
extern "C" void kernel_launch(void* const* d_in, const int* in_sizes, int n_in,
                              void* d_out, int out_size, void* d_ws, size_t ws_size,
                              hipStream_t stream) {
    (void)in_sizes; (void)n_in; (void)out_size; (void)ws_size;
    const float* inputs = (const float*)d_in[0];   // (T,B,V)
    const float* H      = (const float*)d_in[1];   // (L,B,HID)
    const float* Wnet   = (const float*)d_in[2];   // (HID, V+HID)
    const float* bnet   = (const float*)d_in[3];   // (HID,)
    const float* Wdeep  = (const float*)d_in[4];   // (HID, 2*HID)
    const float* bdeep  = (const float*)d_in[5];   // (HID,)
    float* out = (float*)d_out;

    // workspace layout (X first for 8B alignment); ~2.3 MB total
    unsigned long long* X = (unsigned long long*)d_ws;  // 64*2*2*256 u64 = 512 KB
    unsigned* Wq0 = (unsigned*)(X + 64 * 2 * 2 * 256);  // 131072 u32
    unsigned* Wq1 = Wq0 + HH * (HH / 2);                // 131072 u32
    unsigned* Wp0 = Wq1 + HH * (HH / 2);                // 65536 u32
    unsigned* Wp1 = Wp0 + (VV / 2) * HH;                // 131072 u32

    // 1) pack weights (458752 ids / 256 = 1792 blocks)
    hipLaunchKernelGGL(pack_weights, dim3(1792), dim3(256), 0, stream,
                       Wnet, Wdeep, Wq0, Wq1, Wp0, Wp1);

    // 2) pre0 = inputs @ Wx0^T + b_net  -> d_out[0:TBH]
    hipLaunchKernelGGL(xproj_f16, dim3((TT * BB) / 32), dim3(1024),
                       32 * (VV / 2) * sizeof(unsigned), stream,
                       inputs, Wp0, bnet, out, VV);

    // 3) layer-0 scan
    hipLaunchKernelGGL(rnn_scan3, dim3(128), dim3(512), 0, stream,
                       Wq0, H, out, out + TBH, X);

    // 4) pre1 = states0 @ Wx1^T + b_deep (in-place over d_out)
    hipLaunchKernelGGL(xproj_f16, dim3((TT * BB) / 32), dim3(1024),
                       32 * (HH / 2) * sizeof(unsigned), stream,
                       out, Wp1, bdeep, out, HH);

    // 5) layer-1 scan (X reusable: exact-tag matching ignores stale tags)
    hipLaunchKernelGGL(rnn_scan3, dim3(128), dim3(512), 0, stream,
                       Wq1, H + (size_t)BB * HH, out, out + TBH + (size_t)BB * HH, X);
}